// Round 5
// baseline (3145.063 us; speedup 1.0000x reference)
//
#include <hip/hip_runtime.h>
#include <hip/hip_bf16.h>

// LSTM decoder, B=1024, H=300, 256 steps. Output fp32.
// Folded recurrence: W_fold = W_hh + W_ih@W_out (gates from h_t), y = h_t@W_out^T.
// R9: fully wave-decoupled persistent kernel. R8 left ~6.5us/step of latency:
// under-pipelined A-loads (2-kc rotation < MALL latency), two block barriers, and
// y-stores inside the pre-publish drain. Fixes: (1) prefetch ALL 10 kc upfront
// (80x8B agent-atomic loads; 1 wave/SIMD so VGPR budget 512); (2) per-WAVE flags +
// wave-local LDS transpose (wave_barrier + lgkmcnt, no __syncthreads in loop);
// (3) h-store -> vmcnt(0) -> publish -> THEN y stores (off critical path).

typedef __attribute__((ext_vector_type(8))) short bf16x8;
typedef __attribute__((ext_vector_type(4))) float f32x4;
typedef __attribute__((ext_vector_type(2))) unsigned long long u64x2;
typedef unsigned long long u64;

#define MFMA16(a, b, c) __builtin_amdgcn_mfma_f32_16x16x32_bf16((a), (b), (c), 0, 0, 0)

__device__ __forceinline__ float sigf(float x) { return 1.0f / (1.0f + __expf(-x)); }
__device__ __forceinline__ float tanh_fast(float x) { return 2.0f / (1.0f + __expf(-2.0f * x)) - 1.0f; }
__device__ __forceinline__ short f2bf(float x) { __hip_bfloat16 h = __float2bfloat16(x); return *(short*)&h; }
__device__ __forceinline__ float bf2f(short s) { __hip_bfloat16 h; *(short*)&h = s; return __bfloat162float(h); }

__device__ __forceinline__ u64 lda8(const u64* p) {
    return __hip_atomic_load(p, __ATOMIC_RELAXED, __HIP_MEMORY_SCOPE_AGENT);
}
__device__ __forceinline__ void sta8(u64* p, u64 v) {
    __hip_atomic_store(p, v, __ATOMIC_RELAXED, __HIP_MEMORY_SCOPE_AGENT);
}

// ---------- precompute: zero h-frag buffers + flags, copy W_out rows + b_out ----------
__global__ void build_kernel(const float* __restrict__ W_out, const float* __restrict__ b_out,
                             float* __restrict__ W_big, float* __restrict__ bias_big,
                             unsigned int* __restrict__ hfrag_zero, unsigned int* __restrict__ flags) {
    int stride = gridDim.x * blockDim.x;
    int idx = blockIdx.x * blockDim.x + threadIdx.x;
    for (int i = idx; i < 655360; i += stride) hfrag_zero[i] = 0u;  // 4 x 327680 shorts
    for (int i = idx; i < 300 * 300; i += stride) W_big[1200 * 300 + i] = W_out[i];
    for (int i = idx; i < 300; i += stride) bias_big[1200 + i] = b_out[i];
    if (idx < 1024) flags[idx] = 0u;
}

// ---------- precompute: W_big rows 0..1199 = W_hh + W_ih @ W_out ----------
__global__ __launch_bounds__(128) void fold_kernel(const float* __restrict__ W_ih,
                                                   const float* __restrict__ W_hh,
                                                   const float* __restrict__ W_out,
                                                   float* __restrict__ W_big) {
    int j = blockIdx.x;  // 0..1199
    __shared__ float row[300];
    for (int m = threadIdx.x; m < 300; m += 128) row[m] = W_ih[j * 300 + m];
    __syncthreads();
    int k0 = threadIdx.x, k1 = threadIdx.x + 128, k2 = threadIdx.x + 256;
    float a0 = 0.f, a1 = 0.f, a2 = 0.f;
    for (int m = 0; m < 300; ++m) {
        float w = row[m];
        a0 += w * W_out[m * 300 + k0];
        a1 += w * W_out[m * 300 + k1];
        if (k2 < 300) a2 += w * W_out[m * 300 + k2];
    }
    W_big[j * 300 + k0] = W_hh[j * 300 + k0] + a0;
    W_big[j * 300 + k1] = W_hh[j * 300 + k1] + a1;
    if (k2 < 300) W_big[j * 300 + k2] = W_hh[j * 300 + k2] + a2;
}

// ---------- precompute: bias_big[0..1199] = b_ih + b_hh + W_ih @ b_out ----------
__global__ __launch_bounds__(64) void bias_fold_kernel(const float* __restrict__ W_ih,
                                                       const float* __restrict__ b_ih,
                                                       const float* __restrict__ b_hh,
                                                       const float* __restrict__ b_out,
                                                       float* __restrict__ bias_big) {
    int j = blockIdx.x;  // 0..1199
    int lane = threadIdx.x;
    float s = 0.f;
    for (int m = lane; m < 300; m += 64) s += W_ih[j * 300 + m] * b_out[m];
    for (int off = 32; off > 0; off >>= 1) s += __shfl_down(s, off);
    if (lane == 0) bias_big[j] = b_ih[j] + b_hh[j] + s;
}

// ---------- precompute: pack W_big into MFMA B-fragment layout, bf16 hi/lo ----------
// tile index = (jt*5 + ch)*10 + kc ; ch 0..3 = gates (row ch*300+j), 4 = y (row 1200+j).
__global__ __launch_bounds__(64) void pack_w_kernel(const float* __restrict__ W_big,
                                                    short* __restrict__ Wh, short* __restrict__ Wl) {
    int tile = blockIdx.x;  // 0..949
    int jt = tile / 50;
    int rem = tile - jt * 50;
    int ch = rem / 10;
    int kc = rem - ch * 10;
    int lane = threadIdx.x;
    int j = jt * 16 + (lane & 15);
    int kbase = kc * 32 + (lane >> 4) * 8;
    int r = (ch < 4) ? (ch * 300 + j) : (1200 + j);
    size_t base = (size_t)tile * 512 + (size_t)lane * 8;
#pragma unroll
    for (int jj = 0; jj < 8; ++jj) {
        int k = kbase + jj;
        float v = (j < 300 && k < 300) ? W_big[(size_t)r * 300 + k] : 0.f;
        short hi = f2bf(v);
        short lo = f2bf(v - bf2f(hi));
        Wh[base + jj] = hi;
        Wl[base + jj] = lo;
    }
}

// ---------- step 0: exact fp32 VALU LSTM cell on [start | h0], K=600 ----------
__global__ __launch_bounds__(128) void step0_kernel(
    const float* __restrict__ x_in, const float* __restrict__ h_in,
    const float* __restrict__ W_ih, const float* __restrict__ W_hh,
    const float* __restrict__ b_ih, const float* __restrict__ b_hh,
    const float* __restrict__ c_in, float* __restrict__ c_out,
    float* __restrict__ h_out) {
    __shared__ float hs[16][68];
    __shared__ float wsm[16][32];
    const int t = threadIdx.x;
    const int bm0 = blockIdx.x * 64;
    const int jg0 = blockIdx.y * 8;

    const int row_idx = t & 31;
    const int wkq = (t >> 5) << 2;
    const int jl = row_idx >> 2, g = row_idx & 3;
    const int grow = jg0 + jl + 300 * g;
    const bool wvalid = (jg0 + jl) < 300;

    float acc[4][4];
#pragma unroll
    for (int i = 0; i < 4; ++i)
#pragma unroll
        for (int q = 0; q < 4; ++q) acc[i][q] = 0.f;

    for (int it = 0; it < 38; ++it) {
        const int k0 = it << 4;
#pragma unroll
        for (int q = 0; q < 2; ++q) {
            int qi = t + q * 128;
            int bl = qi >> 2;
            int kq = (qi & 3) << 2;
            int kg = k0 + kq;
            float4 hv = make_float4(0.f, 0.f, 0.f, 0.f);
            if (kg < 600) {
                const float* src = (kg < 300) ? (x_in + (size_t)(bm0 + bl) * 300 + kg)
                                              : (h_in + (size_t)(bm0 + bl) * 300 + (kg - 300));
                hv = *(const float4*)src;
            }
            hs[kq + 0][bl] = hv.x;
            hs[kq + 1][bl] = hv.y;
            hs[kq + 2][bl] = hv.z;
            hs[kq + 3][bl] = hv.w;
        }
        {
            int kg = k0 + wkq;
            float4 wv = make_float4(0.f, 0.f, 0.f, 0.f);
            if (wvalid && kg < 600) {
                const float* src = (kg < 300) ? (W_ih + (size_t)grow * 300 + kg)
                                              : (W_hh + (size_t)grow * 300 + (kg - 300));
                wv = *(const float4*)src;
            }
            wsm[wkq + 0][row_idx] = wv.x;
            wsm[wkq + 1][row_idx] = wv.y;
            wsm[wkq + 2][row_idx] = wv.z;
            wsm[wkq + 3][row_idx] = wv.w;
        }
        __syncthreads();
        const int bs4 = (t & 15) << 2;
        const int c4 = (t >> 4) << 2;
#pragma unroll
        for (int k = 0; k < 16; ++k) {
            float4 hv = *(const float4*)&hs[k][bs4];
            float4 wv = *(const float4*)&wsm[k][c4];
            float hvv[4] = {hv.x, hv.y, hv.z, hv.w};
            float wvv[4] = {wv.x, wv.y, wv.z, wv.w};
#pragma unroll
            for (int bi = 0; bi < 4; ++bi)
#pragma unroll
                for (int q = 0; q < 4; ++q) acc[bi][q] += hvv[bi] * wvv[q];
        }
        __syncthreads();
    }

    const int b0 = bm0 + ((t & 15) << 2);
    const int j = jg0 + (t >> 4);
    if (j < 300) {
        const float bi_ = b_ih[j] + b_hh[j];
        const float bf_ = b_ih[j + 300] + b_hh[j + 300];
        const float bg_ = b_ih[j + 600] + b_hh[j + 600];
        const float bo_ = b_ih[j + 900] + b_hh[j + 900];
#pragma unroll
        for (int bi = 0; bi < 4; ++bi) {
            const int b = b0 + bi;
            float ig = sigf(acc[bi][0] + bi_);
            float fg = sigf(acc[bi][1] + bf_);
            float gg = tanh_fast(acc[bi][2] + bg_);
            float og = sigf(acc[bi][3] + bo_);
            float cn = fg * c_in[(size_t)b * 300 + j] + ig * gg;
            c_out[(size_t)b * 300 + j] = cn;
            h_out[(size_t)b * 300 + j] = og * tanh_fast(cn);
        }
    }
}

// ---------- convert h fp32 -> A-fragment layout bf16 hi/lo ----------
__global__ __launch_bounds__(256) void convert_h_kernel(const float* __restrict__ h_row,
                                                        short* __restrict__ Hh, short* __restrict__ Hl) {
    int idx = blockIdx.x * 256 + threadIdx.x;  // 1024*320
    int m = idx / 320;
    int k = idx - m * 320;
    float v = (k < 300) ? h_row[(size_t)m * 300 + k] : 0.f;
    short hi = f2bf(v);
    short lo = f2bf(v - bf2f(hi));
    int chunk = k >> 5;
    int lane = (m & 15) + 16 * ((k & 31) >> 3);
    int slot = k & 7;
    size_t fi = (((size_t)(m >> 4) * 10 + chunk) * 64 + lane) * 8 + slot;
    Hh[fi] = hi;
    Hl[fi] = lo;
}

// ---------- R9 persistent kernel: 152 blocks = 8 groups x 19 jt, 256 thr (4 waves) ----------
// Wave w owns m-tiles {g*8+w, g*8+w+4} end-to-end. No __syncthreads in the loop:
// per-wave flags, wave-local LDS transpose (wave_barrier + lgkmcnt(0)).
// Per step: poll 19 wave-flags -> prefetch ALL A (80x8B agent-atomic) -> MFMA ->
// gate epilogue -> h transpose -> 4x8B agent-atomic h-stores -> vmcnt(0) ->
// publish wave flag -> y nontemporal stores (off critical path).
__global__ __launch_bounds__(256, 1) void persist_kernel(
    short* __restrict__ H0h, short* __restrict__ H0l,
    short* __restrict__ H1h, short* __restrict__ H1l,
    const short* __restrict__ Wph, const short* __restrict__ Wpl,
    const float* __restrict__ bias, const float* __restrict__ c_init,
    float* __restrict__ out, unsigned* __restrict__ flags) {
    __shared__ __align__(16) short w_hi[50 * 512];   // 51200 B
    __shared__ __align__(16) short w_lo[40 * 512];   // 40960 B
    __shared__ __align__(16) short hst_h[4][512];    // 4096 B (per-wave h hi stage)
    __shared__ __align__(16) short hst_l[4][512];    // 4096 B  => 100352 B total

    const int bid = blockIdx.x;
    const int g = bid / 19;         // row group: rows g*128 .. +128
    const int jt = bid - g * 19;    // j tile: cols jt*16 .. +16
    const int tid = threadIdx.x;
    const int wave = tid >> 6;
    const int lane = tid & 63;

    // one-time: W tiles for this jt -> LDS
    {
        const int4* s1 = (const int4*)(Wph + (size_t)jt * 25600);
        int4* d1 = (int4*)w_hi;
        for (int i = tid; i < 3200; i += 256) d1[i] = s1[i];
        const int4* s2 = (const int4*)(Wpl + (size_t)jt * 25600);
        int4* d2 = (int4*)w_lo;
        for (int i = tid; i < 2560; i += 256) d2[i] = s2[i];
    }

    const int jl = lane & 15;
    const int jg = jt * 16 + jl;
    const bool jvalid = jg < 300;
    const int mr = (lane >> 4) << 2;
    const int laneo = lane << 3;

    float b_i = 0.f, b_f = 0.f, b_g = 0.f, b_o = 0.f, b_y = 0.f;
    if (jvalid) {
        b_i = bias[jg];
        b_f = bias[300 + jg];
        b_g = bias[600 + jg];
        b_o = bias[900 + jg];
        b_y = bias[1200 + jg];
    }

    const int mt0 = g * 8 + wave;   // this wave's m-tiles: mt0, mt0+4
    float c_reg[8];
#pragma unroll
    for (int mti = 0; mti < 2; ++mti)
#pragma unroll
        for (int r = 0; r < 4; ++r) {
            const int m = (mt0 + 4 * mti) * 16 + mr + r;
            c_reg[mti * 4 + r] = jvalid ? c_init[(size_t)m * 300 + jg] : 0.f;
        }

    // A addressing in u64 units: fragment (mt,kc,lane) at (mt*640 + kc*64 + lane)*2
    const int iA2 = (mt0 * 640 + lane) * 2;
    const int chunk = jt >> 1;
    unsigned* fpoll_p = flags + ((g * 19 + (lane < 19 ? lane : 18)) * 4 + wave);
    unsigned* fpub_p = flags + ((g * 19 + jt) * 4 + wave);

    // h store-out decomposition (wave-local): lane -> (tile, row, half) 16B run
    const int so_tile = lane >> 5;        // 0..1
    const int so_row = (lane >> 1) & 15;  // 0..15
    const int so_half = lane & 1;         // 0..1
    const int so_off = (so_tile * 16 + so_row) * 16 + so_half * 8;  // shorts
    const size_t so_bi =
        ((size_t)((mt0 + 4 * so_tile) * 10 + chunk) * 64 +
         (so_row + ((2 * (jt & 1) + so_half) << 4))) * 2;

    __syncthreads();  // W in LDS ready (only barrier in the kernel)

#pragma unroll 1
    for (int tt = 1; tt <= 256; ++tt) {
        const short* Ah8 = (tt & 1) ? H0h : H1h;
        const short* Al8 = (tt & 1) ? H0l : H1l;
        short* Bh8 = (tt & 1) ? H1h : H0h;
        short* Bl8 = (tt & 1) ? H1l : H0l;
        float* yo = out + (size_t)(tt - 1) * 307200;

        // wait for the 19 producers of this (group, wave-plane) to finish step tt-1
        {
            const unsigned target = (unsigned)(tt - 1);
            while (true) {
                unsigned fv = __hip_atomic_load(fpoll_p, __ATOMIC_RELAXED,
                                                __HIP_MEMORY_SCOPE_AGENT);
                if (__all((int)((lane >= 19) | (fv >= target)))) break;
                __builtin_amdgcn_s_sleep(1);
            }
        }

        const u64* A2h = (const u64*)Ah8 + iA2;
        const u64* A2l = (const u64*)Al8 + iA2;

        // prefetch the ENTIRE step's A fragments (80 x 8B agent-atomic loads)
        u64 f0h[10][2], f0l[10][2], f1h[10][2], f1l[10][2];
#pragma unroll
        for (int kc = 0; kc < 10; ++kc) {
            f0h[kc][0] = lda8(A2h + kc * 128);
            f0h[kc][1] = lda8(A2h + kc * 128 + 1);
            f0l[kc][0] = lda8(A2l + kc * 128);
            f0l[kc][1] = lda8(A2l + kc * 128 + 1);
            f1h[kc][0] = lda8(A2h + 5120 + kc * 128);
            f1h[kc][1] = lda8(A2h + 5120 + kc * 128 + 1);
            f1l[kc][0] = lda8(A2l + 5120 + kc * 128);
            f1l[kc][1] = lda8(A2l + 5120 + kc * 128 + 1);
        }

        f32x4 acc[4][2];
        f32x4 accy[2];
#pragma unroll
        for (int ch = 0; ch < 4; ++ch) {
            acc[ch][0] = (f32x4){0.f, 0.f, 0.f, 0.f};
            acc[ch][1] = (f32x4){0.f, 0.f, 0.f, 0.f};
        }
        accy[0] = (f32x4){0.f, 0.f, 0.f, 0.f};
        accy[1] = (f32x4){0.f, 0.f, 0.f, 0.f};

#pragma unroll
        for (int kc = 0; kc < 10; ++kc) {
            u64x2 t0h, t0l, t1h, t1l;
            t0h.x = f0h[kc][0]; t0h.y = f0h[kc][1];
            t0l.x = f0l[kc][0]; t0l.y = f0l[kc][1];
            t1h.x = f1h[kc][0]; t1h.y = f1h[kc][1];
            t1l.x = f1l[kc][0]; t1l.y = f1l[kc][1];
            const bf16x8 a0h = (bf16x8)t0h;
            const bf16x8 a0l = (bf16x8)t0l;
            const bf16x8 a1h = (bf16x8)t1h;
            const bf16x8 a1l = (bf16x8)t1l;
#pragma unroll
            for (int ch = 0; ch < 4; ++ch) {
                const bf16x8 bh = *(const bf16x8*)(w_hi + ((ch * 10 + kc) << 9) + laneo);
                const bf16x8 bl = *(const bf16x8*)(w_lo + ((ch * 10 + kc) << 9) + laneo);
                acc[ch][0] = MFMA16(a0h, bh, acc[ch][0]);
                acc[ch][0] = MFMA16(a0l, bh, acc[ch][0]);
                acc[ch][0] = MFMA16(a0h, bl, acc[ch][0]);
                acc[ch][1] = MFMA16(a1h, bh, acc[ch][1]);
                acc[ch][1] = MFMA16(a1l, bh, acc[ch][1]);
                acc[ch][1] = MFMA16(a1h, bl, acc[ch][1]);
            }
            const bf16x8 by = *(const bf16x8*)(w_hi + ((40 + kc) << 9) + laneo);
            accy[0] = MFMA16(a0h, by, accy[0]);
            accy[0] = MFMA16(a0l, by, accy[0]);
            accy[1] = MFMA16(a1h, by, accy[1]);
            accy[1] = MFMA16(a1l, by, accy[1]);
        }

        // gate epilogue -> wave-local LDS transpose stage
#pragma unroll
        for (int mti = 0; mti < 2; ++mti) {
#pragma unroll
            for (int r = 0; r < 4; ++r) {
                const float gi = acc[0][mti][r] + b_i;
                const float gf = acc[1][mti][r] + b_f;
                const float gg = acc[2][mti][r] + b_g;
                const float go_ = acc[3][mti][r] + b_o;
                const float iv = sigf(gi), fv = sigf(gf), gv = tanh_fast(gg), ov = sigf(go_);
                const float cn = fv * c_reg[mti * 4 + r] + iv * gv;
                c_reg[mti * 4 + r] = cn;
                const float hv = ov * tanh_fast(cn);
                const short hb = f2bf(hv);
                const short lb = f2bf(hv - bf2f(hb));
                const int si = (mti * 16 + mr + r) * 16 + jl;
                hst_h[wave][si] = hb;
                hst_l[wave][si] = lb;
            }
        }
        __builtin_amdgcn_wave_barrier();
        asm volatile("s_waitcnt lgkmcnt(0)" ::: "memory");
        __builtin_amdgcn_sched_barrier(0);

        // store-out: one 16B hi + 16B lo run per lane via 8B agent-atomic stores
        {
            const u64* sh = (const u64*)&hst_h[wave][so_off];
            const u64* sl = (const u64*)&hst_l[wave][so_off];
            sta8((u64*)Bh8 + so_bi, sh[0]);
            sta8((u64*)Bh8 + so_bi + 1, sh[1]);
            sta8((u64*)Bl8 + so_bi, sl[0]);
            sta8((u64*)Bl8 + so_bi + 1, sl[1]);
        }
        asm volatile("s_waitcnt vmcnt(0)" ::: "memory");  // h visible at MALL
        if (lane == 0) {
            __hip_atomic_store(fpub_p, (unsigned)tt, __ATOMIC_RELAXED,
                               __HIP_MEMORY_SCOPE_AGENT);
        }

        // y output off the critical path (overlaps next step's poll/prefetch)
        if (jvalid) {
#pragma unroll
            for (int mti = 0; mti < 2; ++mti)
#pragma unroll
                for (int r = 0; r < 4; ++r) {
                    const int m = (mt0 + 4 * mti) * 16 + mr + r;
                    __builtin_nontemporal_store(accy[mti][r] + b_y, yo + (size_t)m * 300 + jg);
                }
        }
    }
}

extern "C" void kernel_launch(void* const* d_in, const int* in_sizes, int n_in,
                              void* d_out, int out_size, void* d_ws, size_t ws_size,
                              hipStream_t stream) {
    const float* h0 = (const float*)d_in[0];
    const float* c0 = (const float*)d_in[1];
    const float* start = (const float*)d_in[2];
    const float* W_ih = (const float*)d_in[3];
    const float* W_hh = (const float*)d_in[4];
    const float* b_ih = (const float*)d_in[5];
    const float* b_hh = (const float*)d_in[6];
    const float* W_out = (const float*)d_in[7];
    const float* b_out = (const float*)d_in[8];
    float* out = (float*)d_out;

    float* wsf = (float*)d_ws;
    float* W_big = wsf;               // 450000
    float* bias_big = wsf + 450000;   // 1504
    float* c_ws = wsf + 451504;       // 307200
    float* h_row = wsf + 758704;      // 307200
    short* wss = (short*)(wsf + 1065904);
    short* Wh = wss;                  // 486400
    short* Wl = wss + 486400;         // 486400
    short* H0h = wss + 972800;        // 327680
    short* H0l = wss + 1300480;       // 327680
    short* H1h = wss + 1628160;       // 327680
    short* H1l = wss + 1955840;       // 327680
    unsigned* flags = (unsigned*)(wss + 2283520);  // 608 uints used (1024 zeroed)

    build_kernel<<<2816, 256, 0, stream>>>(W_out, b_out, W_big, bias_big, (unsigned int*)H0h, flags);
    fold_kernel<<<1200, 128, 0, stream>>>(W_ih, W_hh, W_out, W_big);
    bias_fold_kernel<<<1200, 64, 0, stream>>>(W_ih, b_ih, b_hh, b_out, bias_big);
    pack_w_kernel<<<950, 64, 0, stream>>>(W_big, Wh, Wl);

    // step 0 (ref iteration 0): exact fp32; h_1 -> h_row, c_1 -> c_ws
    step0_kernel<<<dim3(16, 38), 128, 0, stream>>>(start, h0, W_ih, W_hh, b_ih, b_hh,
                                                   c0, c_ws, h_row);
    convert_h_kernel<<<1280, 256, 0, stream>>>(h_row, H0h, H0l);

    // tt = 1..256 inside one wave-decoupled persistent kernel (152 blocks, 1/CU)
    persist_kernel<<<152, 256, 0, stream>>>(H0h, H0l, H1h, H1l, Wh, Wl,
                                            bias_big, c_ws, out, flags);
}